// Round 8
// baseline (865.740 us; speedup 1.0000x reference)
//
#include <hip/hip_runtime.h>
#include <hip/hip_bf16.h>

#define N_NODES 200000
#define N_GRAPHS 1024
#define D 16
#define NEDGE 6400000

#define BNODES 256                 // nodes per bucket: bucket = dst >> 8
#define NBUK 782                   // ceil(200000/256)
#define NCH 512                    // edge chunks
#define ECHUNK 12500               // NEDGE / NCH (exact)
#define OSTRIDE (NBUK + 1)         // 783
#define CAP 9216                   // bucket slab capacity (mean 8192, sd ~90 -> 11 sigma)
#define GSEG 3125                  // gather blocks per pass: 64 nodes x 4 lanes = 256
#define PLSZ ((size_t)N_NODES * 8) // elements per bf16 plane table (3.2 MB)

// ---- pA (fused R+L): sort one 12500-edge chunk by bucket in LDS, coalesced writeback ----
__global__ __launch_bounds__(1024) void pA(
        const int* __restrict__ srcR, const int* __restrict__ dstR,
        const int* __restrict__ srcL, const int* __restrict__ dstL,
        unsigned int* __restrict__ slabC_R, unsigned int* __restrict__ slabC_L,
        int* __restrict__ offsT_R, int* __restrict__ offsT_L) {
    const int* src = blockIdx.y ? srcL : srcR;
    const int* dst = blockIdx.y ? dstL : dstR;
    unsigned int* slabC = blockIdx.y ? slabC_L : slabC_R;
    int* offsT = blockIdx.y ? offsT_L : offsT_R;

    __shared__ unsigned int stage[ECHUNK];   // 50 KB
    __shared__ int lh[NBUK];
    __shared__ int lcur[NBUK];
    __shared__ int wsum[16];
    int t = threadIdx.x;
    int wave = t >> 6, lane = t & 63;
    int c = blockIdx.x;
    int base = c * ECHUNK;

    for (int k = t; k < NBUK; k += 1024) lh[k] = 0;
    __syncthreads();
    for (int e = t; e < ECHUNK; e += 1024)
        atomicAdd(&lh[((unsigned int)dst[base + e]) >> 8], 1);
    __syncthreads();

    int v = (t < NBUK) ? lh[t] : 0;
    int x = v;
#pragma unroll
    for (int d0 = 1; d0 < 64; d0 <<= 1) {
        int y = __shfl_up(x, d0, 64);
        if (lane >= d0) x += y;
    }
    if (lane == 63) wsum[wave] = x;
    __syncthreads();
    if (wave == 0 && lane < 16) {
        int s = wsum[lane];
#pragma unroll
        for (int d0 = 1; d0 < 16; d0 <<= 1) {
            int y = __shfl_up(s, d0, 64);
            if (lane >= d0) s += y;
        }
        wsum[lane] = s;
    }
    __syncthreads();
    int excl = x - v + (wave ? wsum[wave - 1] : 0);
    if (t < NBUK) lcur[t] = excl;
    __syncthreads();

    for (int e = t; e < ECHUNK; e += 1024) {
        int d = dst[base + e];
        int s = src[base + e];
        int pos = atomicAdd(&lcur[d >> 8], 1);
        stage[pos] = ((unsigned int)(d & 255) << 18) | (unsigned int)s;
    }
    __syncthreads();
    for (int e = t; e < ECHUNK; e += 1024) slabC[base + e] = stage[e];
    if (t < NBUK) offsT[c * OSTRIDE + t] = excl;
    if (t == 0) offsT[c * OSTRIDE + NBUK] = ECHUNK;
}

// ---- transpose offsT [NCH][OSTRIDE] -> offsTT [OSTRIDE][NCH] ----
__global__ __launch_bounds__(256) void tr_kernel(
        const int* __restrict__ offsT_R, const int* __restrict__ offsT_L,
        int* __restrict__ offsTT_R, int* __restrict__ offsTT_L) {
    const int* in = blockIdx.z ? offsT_L : offsT_R;
    int* outp = blockIdx.z ? offsTT_L : offsTT_R;
    __shared__ int tile[32][33];
    int lx = threadIdx.x & 31, ly = threadIdx.x >> 5;
#pragma unroll
    for (int r = 0; r < 32; r += 8) {
        int row = blockIdx.y * 32 + ly + r;
        int col = blockIdx.x * 32 + lx;
        if (col < OSTRIDE) tile[ly + r][lx] = in[row * OSTRIDE + col];
    }
    __syncthreads();
#pragma unroll
    for (int r = 0; r < 32; r += 8) {
        int orow = blockIdx.x * 32 + ly + r;
        int ocol = blockIdx.y * 32 + lx;
        if (orow < OSTRIDE) outp[orow * NCH + ocol] = tile[lx][ly + r];
    }
}

// ---- pB (fused R+L): single-pass per-bucket counting sort (LDS-staged input) ----
__global__ __launch_bounds__(256) void pB(
        const unsigned int* __restrict__ slabC_R, const unsigned int* __restrict__ slabC_L,
        const int* __restrict__ offsTT_R, const int* __restrict__ offsTT_L,
        unsigned int* __restrict__ slabR, unsigned int* __restrict__ slabL,
        int2* __restrict__ metaR, int2* __restrict__ metaL,
        float* __restrict__ disR, float* __restrict__ disL) {
    int y = blockIdx.y;
    const unsigned int* slabC = y ? slabC_L : slabC_R;
    const int* offsTT = y ? offsTT_L : offsTT_R;
    unsigned int* slab = y ? slabL : slabR;
    int2* meta = y ? metaL : metaR;
    float* dis = y ? disL : disR;

    __shared__ unsigned int sin_[CAP];
    __shared__ unsigned int sout[CAP];
    __shared__ int hcnt[BNODES], hoff[BNODES], hcur[BNODES];
    __shared__ int wtot[4];
    __shared__ int totc;
    int t = threadIdx.x;
    int lane = t & 63, wave = t >> 6;
    int b = blockIdx.x;

    int a0 = offsTT[b * NCH + t],        e0 = offsTT[(b + 1) * NCH + t];
    int a1 = offsTT[b * NCH + t + 256],  e1 = offsTT[(b + 1) * NCH + t + 256];
    int len = (e0 - a0) + (e1 - a1);

    int x = len;
#pragma unroll
    for (int d0 = 1; d0 < 64; d0 <<= 1) {
        int yy = __shfl_up(x, d0, 64);
        if (lane >= d0) x += yy;
    }
    if (lane == 63) wtot[wave] = x;
    hcnt[t] = 0;
    __syncthreads();
    int pre = 0;
    for (int w2 = 0; w2 < wave; w2++) pre += wtot[w2];
    int sbase = x - len + pre;
    if (t == 255) totc = sbase + len;
    __syncthreads();

    int p = sbase;
    {
        int cb = t * ECHUNK;
        for (int i = (a0 & ~3); i < e0; i += 4) {
            uint4 v = *(const uint4*)(slabC + cb + i);
            unsigned int vv[4] = {v.x, v.y, v.z, v.w};
#pragma unroll
            for (int k = 0; k < 4; k++) {
                int idx = i + k;
                if (idx >= a0 && idx < e0) { if (p < CAP) sin_[p] = vv[k]; p++; }
            }
        }
        cb = (t + 256) * ECHUNK;
        for (int i = (a1 & ~3); i < e1; i += 4) {
            uint4 v = *(const uint4*)(slabC + cb + i);
            unsigned int vv[4] = {v.x, v.y, v.z, v.w};
#pragma unroll
            for (int k = 0; k < 4; k++) {
                int idx = i + k;
                if (idx >= a1 && idx < e1) { if (p < CAP) sin_[p] = vv[k]; p++; }
            }
        }
    }
    __syncthreads();
    int cnt = totc;
    if (cnt > CAP) cnt = CAP;

    for (int i = t; i < cnt; i += 256) atomicAdd(&hcnt[sin_[i] >> 18], 1);
    __syncthreads();

    int v2 = hcnt[t];
    int x2 = v2;
#pragma unroll
    for (int d0 = 1; d0 < 64; d0 <<= 1) {
        int yy = __shfl_up(x2, d0, 64);
        if (lane >= d0) x2 += yy;
    }
    if (lane == 63) wtot[wave] = x2;
    __syncthreads();
    int pre2 = 0;
    for (int w2 = 0; w2 < wave; w2++) pre2 += wtot[w2];
    int ex = x2 - v2 + pre2;
    hoff[t] = ex;
    hcur[t] = ex;
    __syncthreads();

    for (int i = t; i < cnt; i += 256) {
        unsigned int r = sin_[i];
        int pp = atomicAdd(&hcur[r >> 18], 1);
        if (pp < CAP) sout[pp] = r & 0x3FFFFu;
    }
    __syncthreads();

    int gb = b * CAP;
    for (int i = t; i < cnt; i += 256) slab[gb + i] = sout[i];
    int node = (b << 8) + t;
    if (node < N_NODES) {
        meta[node] = make_int2(gb + hoff[t], gb + hoff[t] + hcnt[t]);
        dis[node] = rsqrtf((float)hcnt[t] + 1.0f);
    }
}

// ---- t1 (fused R+L): hs1 planes = bf16( (emb[ids[i]] @ W1) * dis[i] ) ----
__global__ __launch_bounds__(256) void t1_kernel(
        const int* __restrict__ idsR, const int* __restrict__ idsL,
        const float* __restrict__ emb, const float* __restrict__ W,
        const float* __restrict__ disR, const float* __restrict__ disL,
        __hip_bfloat16* __restrict__ h0R, __hip_bfloat16* __restrict__ h1R,
        __hip_bfloat16* __restrict__ h0L, __hip_bfloat16* __restrict__ h1L) {
    int y = blockIdx.y;
    const int* ids = y ? idsL : idsR;
    const float* dis = y ? disL : disR;
    __hip_bfloat16* h0 = y ? h0L : h0R;
    __hip_bfloat16* h1 = y ? h1L : h1R;
    __shared__ float sW[D][D];
    __shared__ float sx[16][D + 1];
    int t = threadIdx.x;
    int j = t & 15, g = t >> 4;
    sW[g][j] = W[t];
    int i = (blockIdx.x << 4) + g;
    sx[g][j] = emb[(size_t)ids[i] * D + j];
    __syncthreads();
    float acc = 0.f;
#pragma unroll
    for (int k = 0; k < D; k++) acc += sx[g][k] * sW[k][j];
    __hip_bfloat16* hp = (j < 8) ? h0 : h1;
    hp[(size_t)i * 8 + (j & 7)] = __float2bfloat16(acc * dis[i]);
}

// ---- g1 pass (one protein, one plane): gather + relu -> x plane (bf16) ----
__global__ __launch_bounds__(256) void g1_kernel(
        const int2* __restrict__ meta, const unsigned int* __restrict__ csr,
        const __hip_bfloat16* __restrict__ hp, const float* __restrict__ dis,
        const float* __restrict__ bias8, __hip_bfloat16* __restrict__ outp) {
    int t = threadIdx.x;
    int jp = t & 3, g = t >> 2;
    int i = (blockIdx.x << 6) + g;
    int2 be = meta[i];
    float2 acc = __bfloat1622float2(*(const __hip_bfloat162*)(hp + (size_t)i * 8 + 2 * jp));
    int e = be.x, end = be.y;
    for (; e + 4 <= end; e += 4) {
        unsigned int my = __builtin_nontemporal_load(csr + e + jp);
#pragma unroll
        for (int n = 0; n < 4; n++) {
            int s = __shfl((int)my, n, 4);
            float2 f = __bfloat1622float2(
                *(const __hip_bfloat162*)(hp + (size_t)s * 8 + 2 * jp));
            acc.x += f.x; acc.y += f.y;
        }
    }
    for (; e < end; e++) {
        int s = (int)__builtin_nontemporal_load(csr + e);
        float2 f = __bfloat1622float2(
            *(const __hip_bfloat162*)(hp + (size_t)s * 8 + 2 * jp));
        acc.x += f.x; acc.y += f.y;
    }
    float di = dis[i];
    float v0 = fmaxf(acc.x * di + bias8[2 * jp], 0.f);
    float v1 = fmaxf(acc.y * di + bias8[2 * jp + 1], 0.f);
    __hip_bfloat162 r = __float22bfloat162_rn(make_float2(v0, v1));
    __builtin_nontemporal_store(*(unsigned int*)&r,
                                (unsigned int*)(outp + (size_t)i * 8 + 2 * jp));
}

// ---- t2 (fused R+L): hs2 planes = bf16( (x @ W2) * dis ) ----
__global__ __launch_bounds__(256) void t2_kernel(
        const __hip_bfloat16* __restrict__ x0R, const __hip_bfloat16* __restrict__ x1R,
        const __hip_bfloat16* __restrict__ x0L, const __hip_bfloat16* __restrict__ x1L,
        const float* __restrict__ W,
        const float* __restrict__ disR, const float* __restrict__ disL,
        __hip_bfloat16* __restrict__ h0R, __hip_bfloat16* __restrict__ h1R,
        __hip_bfloat16* __restrict__ h0L, __hip_bfloat16* __restrict__ h1L) {
    int y = blockIdx.y;
    const __hip_bfloat16* x0 = y ? x0L : x0R;
    const __hip_bfloat16* x1 = y ? x1L : x1R;
    const float* dis = y ? disL : disR;
    __hip_bfloat16* h0 = y ? h0L : h0R;
    __hip_bfloat16* h1 = y ? h1L : h1R;
    __shared__ float sW[D][D];
    __shared__ float sx[16][D + 1];
    int t = threadIdx.x;
    int j = t & 15, g = t >> 4;
    sW[g][j] = W[t];
    int i = (blockIdx.x << 4) + g;
    const __hip_bfloat16* xp = (j < 8) ? x0 : x1;
    sx[g][j] = __bfloat162float(xp[(size_t)i * 8 + (j & 7)]);
    __syncthreads();
    float acc = 0.f;
#pragma unroll
    for (int k = 0; k < D; k++) acc += sx[g][k] * sW[k][j];
    __hip_bfloat16* hp = (j < 8) ? h0 : h1;
    hp[(size_t)i * 8 + (j & 7)] = __float2bfloat16(acc * dis[i]);
}

// ---- g2 pass (one protein, one plane): gather + bias + fused mean-pool ----
__global__ __launch_bounds__(256) void g2_kernel(
        const int2* __restrict__ meta, const unsigned int* __restrict__ csr,
        const __hip_bfloat16* __restrict__ hp, const float* __restrict__ dis,
        const float* __restrict__ bias8, const int* __restrict__ batch,
        float* __restrict__ sums8, float* __restrict__ cnt, int addCnt) {
    __shared__ float sv[64][9];
    __shared__ int sb[64];
    int t = threadIdx.x;
    int jp = t & 3, g = t >> 2;
    int i = (blockIdx.x << 6) + g;
    int2 be = meta[i];
    float2 acc = __bfloat1622float2(*(const __hip_bfloat162*)(hp + (size_t)i * 8 + 2 * jp));
    int e = be.x, end = be.y;
    for (; e + 4 <= end; e += 4) {
        unsigned int my = __builtin_nontemporal_load(csr + e + jp);
#pragma unroll
        for (int n = 0; n < 4; n++) {
            int s = __shfl((int)my, n, 4);
            float2 f = __bfloat1622float2(
                *(const __hip_bfloat162*)(hp + (size_t)s * 8 + 2 * jp));
            acc.x += f.x; acc.y += f.y;
        }
    }
    for (; e < end; e++) {
        int s = (int)__builtin_nontemporal_load(csr + e);
        float2 f = __bfloat1622float2(
            *(const __hip_bfloat162*)(hp + (size_t)s * 8 + 2 * jp));
        acc.x += f.x; acc.y += f.y;
    }
    float di = dis[i];
    sv[g][2 * jp]     = acc.x * di + bias8[2 * jp];
    sv[g][2 * jp + 1] = acc.y * di + bias8[2 * jp + 1];
    if (jp == 0) sb[g] = batch[i];
    __syncthreads();
    int bi = sb[g];
    bool runend = (g == 63) || (sb[g + 1] != bi);
    if (runend) {
        float s0 = 0.f, s1 = 0.f;
        int gg = g;
        while (gg >= 0 && sb[gg] == bi) { s0 += sv[gg][2 * jp]; s1 += sv[gg][2 * jp + 1]; gg--; }
        atomicAdd(&sums8[(size_t)bi * D + 2 * jp], s0);
        atomicAdd(&sums8[(size_t)bi * D + 2 * jp + 1], s1);
        if (jp == 0 && addCnt) atomicAdd(&cnt[bi], (float)(g - gg));
    }
}

// ---- final FC ----
__global__ void final_kernel(const float* __restrict__ rs, const float* __restrict__ rc,
                             const float* __restrict__ ls, const float* __restrict__ lc,
                             const float* __restrict__ fcW, const float* __restrict__ fcb,
                             float* __restrict__ out) {
    int b = blockIdx.x * blockDim.x + threadIdx.x;
    if (b >= N_GRAPHS) return;
    float hc[2 * D];
    float rn = fmaxf(rc[b], 1.f), ln = fmaxf(lc[b], 1.f);
#pragma unroll
    for (int j = 0; j < D; j++) {
        hc[j]     = rs[b * D + j] / rn;
        hc[D + j] = ls[b * D + j] / ln;
    }
#pragma unroll
    for (int c = 0; c < 6; c++) {
        float acc = fcb[c];
#pragma unroll
        for (int j = 0; j < 2 * D; j++) acc += hc[j] * fcW[c * 2 * D + j];
        if (c < 3) out[b * 3 + c] = acc;
        else       out[N_GRAPHS * 3 + b * 3 + (c - 3)] = acc;
    }
}

extern "C" void kernel_launch(void* const* d_in, const int* in_sizes, int n_in,
                              void* d_out, int out_size, void* d_ws, size_t ws_size,
                              hipStream_t stream) {
    const float* emb = (const float*)d_in[0];
    const float* W1  = (const float*)d_in[1];
    const float* b1  = (const float*)d_in[2];
    const float* W2  = (const float*)d_in[3];
    const float* b2  = (const float*)d_in[4];
    const float* fcW = (const float*)d_in[5];
    const float* fcb = (const float*)d_in[6];
    const int* rx = (const int*)d_in[7];
    const int* re = (const int*)d_in[8];
    const int* rb = (const int*)d_in[9];
    const int* lx = (const int*)d_in[10];
    const int* le = (const int*)d_in[11];
    const int* lb = (const int*)d_in[12];
    float* out = (float*)d_out;

    char* w = (char*)d_ws;
    // slabC region (51.2 MB), dead after pB; 12 bf16 plane tables (38.4 MB) overlay it.
    unsigned int* slabC_R = (unsigned int*)w;
    __hip_bfloat16* pt = (__hip_bfloat16*)w;
    __hip_bfloat16* h1_0R = pt;              __hip_bfloat16* h1_1R = pt + PLSZ;
    __hip_bfloat16* h1_0L = pt + 2 * PLSZ;   __hip_bfloat16* h1_1L = pt + 3 * PLSZ;
    __hip_bfloat16* h2_0R = pt + 4 * PLSZ;   __hip_bfloat16* h2_1R = pt + 5 * PLSZ;
    __hip_bfloat16* h2_0L = pt + 6 * PLSZ;   __hip_bfloat16* h2_1L = pt + 7 * PLSZ;
    __hip_bfloat16* x_0R  = pt + 8 * PLSZ;   __hip_bfloat16* x_1R  = pt + 9 * PLSZ;
    __hip_bfloat16* x_0L  = pt + 10 * PLSZ;  __hip_bfloat16* x_1L  = pt + 11 * PLSZ;
    w += (size_t)NEDGE * 4;
    unsigned int* slabC_L = (unsigned int*)w;  w += (size_t)NEDGE * 4;
    unsigned int* slabR = (unsigned int*)w;    w += (size_t)NBUK * CAP * 4;
    unsigned int* slabL = (unsigned int*)w;    w += (size_t)NBUK * CAP * 4;
    int* offsT_R = (int*)w;                    w += (size_t)NCH * OSTRIDE * 4;
    int* offsT_L = (int*)w;                    w += (size_t)NCH * OSTRIDE * 4;
    int* offsTT_R = (int*)w;                   w += (size_t)OSTRIDE * NCH * 4;
    int* offsTT_L = (int*)w;                   w += (size_t)OSTRIDE * NCH * 4;
    int2* metaR = (int2*)w;                    w += (size_t)N_NODES * 8;
    int2* metaL = (int2*)w;                    w += (size_t)N_NODES * 8;
    float* disR = (float*)w;                   w += (size_t)N_NODES * 4;
    float* disL = (float*)w;                   w += (size_t)N_NODES * 4;
    float* sums0 = (float*)w;                  w += (size_t)N_GRAPHS * D * 4;
    float* cnt0  = (float*)w;                  w += (size_t)N_GRAPHS * 4;
    float* sums1 = (float*)w;                  w += (size_t)N_GRAPHS * D * 4;
    float* cnt1  = (float*)w;                  w += (size_t)N_GRAPHS * 4;

    const int* srcR = re;  const int* dstR = re + NEDGE;
    const int* srcL = le;  const int* dstL = le + NEDGE;

    hipMemsetAsync(sums0, 0, ((size_t)N_GRAPHS * (D + 1)) * 2 * sizeof(float), stream);

    // ---- CSR build (R+L fused) ----
    pA<<<dim3(NCH, 2), 1024, 0, stream>>>(srcR, dstR, srcL, dstL,
                                          slabC_R, slabC_L, offsT_R, offsT_L);
    tr_kernel<<<dim3((OSTRIDE + 31) / 32, NCH / 32, 2), 256, 0, stream>>>(
        offsT_R, offsT_L, offsTT_R, offsTT_L);
    pB<<<dim3(NBUK, 2), 256, 0, stream>>>(slabC_R, slabC_L, offsTT_R, offsTT_L,
                                          slabR, slabL, metaR, metaL, disR, disL);

    // ---- GCN pipeline, plane-split gathers (one launch per protein x plane) ----
    t1_kernel<<<dim3(12500, 2), 256, 0, stream>>>(rx, lx, emb, W1, disR, disL,
                                                  h1_0R, h1_1R, h1_0L, h1_1L);
    g1_kernel<<<GSEG, 256, 0, stream>>>(metaR, slabR, h1_0R, disR, b1,     x_0R);
    g1_kernel<<<GSEG, 256, 0, stream>>>(metaR, slabR, h1_1R, disR, b1 + 8, x_1R);
    g1_kernel<<<GSEG, 256, 0, stream>>>(metaL, slabL, h1_0L, disL, b1,     x_0L);
    g1_kernel<<<GSEG, 256, 0, stream>>>(metaL, slabL, h1_1L, disL, b1 + 8, x_1L);
    t2_kernel<<<dim3(12500, 2), 256, 0, stream>>>(x_0R, x_1R, x_0L, x_1L, W2, disR, disL,
                                                  h2_0R, h2_1R, h2_0L, h2_1L);
    g2_kernel<<<GSEG, 256, 0, stream>>>(metaR, slabR, h2_0R, disR, b2,     rb, sums0,     cnt0, 1);
    g2_kernel<<<GSEG, 256, 0, stream>>>(metaR, slabR, h2_1R, disR, b2 + 8, rb, sums0 + 8, cnt0, 0);
    g2_kernel<<<GSEG, 256, 0, stream>>>(metaL, slabL, h2_0L, disL, b2,     lb, sums1,     cnt1, 1);
    g2_kernel<<<GSEG, 256, 0, stream>>>(metaL, slabL, h2_1L, disL, b2 + 8, lb, sums1 + 8, cnt1, 0);
    final_kernel<<<(N_GRAPHS + 255) / 256, 256, 0, stream>>>(
        sums0, cnt0, sums1, cnt1, fcW, fcb, out);
}

// Round 9
// 571.905 us; speedup vs baseline: 1.5138x; 1.5138x over previous
//
#include <hip/hip_runtime.h>
#include <hip/hip_bf16.h>

#define N_NODES 200000
#define N_GRAPHS 1024
#define D 16
#define NEDGE 6400000

#define BNODES 256                 // nodes per bucket: bucket = dst >> 8
#define NBUK 782                   // ceil(200000/256)
#define NCH 512                    // edge chunks
#define ECHUNK 12500               // NEDGE / NCH (exact)
#define EC4 (ECHUNK / 4)           // 3125 int4 groups (exact)
#define OSTRIDE (NBUK + 1)         // 783
#define CAP 9216                   // bucket slab capacity (mean 8192, sd ~90 -> 11 sigma)
#define GBLK 12500                 // t1/t2 blocks: 16 nodes x 16 lanes

// ---- pA (fused R+L): sort one 12500-edge chunk by bucket in LDS, coalesced writeback ----
__global__ __launch_bounds__(1024) void pA(
        const int* __restrict__ srcR, const int* __restrict__ dstR,
        const int* __restrict__ srcL, const int* __restrict__ dstL,
        unsigned int* __restrict__ slabC_R, unsigned int* __restrict__ slabC_L,
        int* __restrict__ offsT_R, int* __restrict__ offsT_L) {
    const int* src = blockIdx.y ? srcL : srcR;
    const int* dst = blockIdx.y ? dstL : dstR;
    unsigned int* slabC = blockIdx.y ? slabC_L : slabC_R;
    int* offsT = blockIdx.y ? offsT_L : offsT_R;

    __shared__ unsigned int stage[ECHUNK];   // 50 KB
    __shared__ int lh[NBUK];
    __shared__ int lcur[NBUK];
    __shared__ int wsum[16];
    int t = threadIdx.x;
    int wave = t >> 6, lane = t & 63;
    int c = blockIdx.x;
    int base = c * ECHUNK;                   // 50000 B offset: 16B-aligned for all c
    const int4* dst4 = (const int4*)(dst + base);
    const int4* src4 = (const int4*)(src + base);

    for (int k = t; k < NBUK; k += 1024) lh[k] = 0;
    __syncthreads();
    for (int i = t; i < EC4; i += 1024) {
        int4 d4 = dst4[i];
        atomicAdd(&lh[((unsigned int)d4.x) >> 8], 1);
        atomicAdd(&lh[((unsigned int)d4.y) >> 8], 1);
        atomicAdd(&lh[((unsigned int)d4.z) >> 8], 1);
        atomicAdd(&lh[((unsigned int)d4.w) >> 8], 1);
    }
    __syncthreads();

    int v = (t < NBUK) ? lh[t] : 0;
    int x = v;
#pragma unroll
    for (int d0 = 1; d0 < 64; d0 <<= 1) {
        int y = __shfl_up(x, d0, 64);
        if (lane >= d0) x += y;
    }
    if (lane == 63) wsum[wave] = x;
    __syncthreads();
    if (wave == 0 && lane < 16) {
        int s = wsum[lane];
#pragma unroll
        for (int d0 = 1; d0 < 16; d0 <<= 1) {
            int y = __shfl_up(s, d0, 64);
            if (lane >= d0) s += y;
        }
        wsum[lane] = s;
    }
    __syncthreads();
    int excl = x - v + (wave ? wsum[wave - 1] : 0);
    if (t < NBUK) lcur[t] = excl;
    __syncthreads();

    for (int i = t; i < EC4; i += 1024) {
        int4 d4 = dst4[i];
        int4 s4 = src4[i];
        int dd[4] = {d4.x, d4.y, d4.z, d4.w};
        int ss[4] = {s4.x, s4.y, s4.z, s4.w};
#pragma unroll
        for (int k = 0; k < 4; k++) {
            int pos = atomicAdd(&lcur[dd[k] >> 8], 1);
            stage[pos] = ((unsigned int)(dd[k] & 255) << 18) | (unsigned int)ss[k];
        }
    }
    __syncthreads();
    uint4* out4 = (uint4*)(slabC + base);
    const uint4* st4 = (const uint4*)stage;
    for (int i = t; i < EC4; i += 1024) out4[i] = st4[i];
    if (t < NBUK) offsT[c * OSTRIDE + t] = excl;
    if (t == 0) offsT[c * OSTRIDE + NBUK] = ECHUNK;
}

// ---- transpose offsT [NCH][OSTRIDE] -> offsTT [OSTRIDE][NCH] ----
__global__ __launch_bounds__(256) void tr_kernel(
        const int* __restrict__ offsT_R, const int* __restrict__ offsT_L,
        int* __restrict__ offsTT_R, int* __restrict__ offsTT_L) {
    const int* in = blockIdx.z ? offsT_L : offsT_R;
    int* outp = blockIdx.z ? offsTT_L : offsTT_R;
    __shared__ int tile[32][33];
    int lx = threadIdx.x & 31, ly = threadIdx.x >> 5;
#pragma unroll
    for (int r = 0; r < 32; r += 8) {
        int row = blockIdx.y * 32 + ly + r;
        int col = blockIdx.x * 32 + lx;
        if (col < OSTRIDE) tile[ly + r][lx] = in[row * OSTRIDE + col];
    }
    __syncthreads();
#pragma unroll
    for (int r = 0; r < 32; r += 8) {
        int orow = blockIdx.x * 32 + ly + r;
        int ocol = blockIdx.y * 32 + lx;
        if (orow < OSTRIDE) outp[orow * NCH + ocol] = tile[lx][ly + r];
    }
}

// ---- pB (fused R+L): single-pass counting sort; scattered 4B writes into the
//      bucket's dense 36KB global window (L2 merges into full lines) ----
__global__ __launch_bounds__(256) void pB(
        const unsigned int* __restrict__ slabC_R, const unsigned int* __restrict__ slabC_L,
        const int* __restrict__ offsTT_R, const int* __restrict__ offsTT_L,
        unsigned int* __restrict__ slabR, unsigned int* __restrict__ slabL,
        int2* __restrict__ metaR, int2* __restrict__ metaL,
        float* __restrict__ disR, float* __restrict__ disL) {
    int y = blockIdx.y;
    const unsigned int* slabC = y ? slabC_L : slabC_R;
    const int* offsTT = y ? offsTT_L : offsTT_R;
    unsigned int* slab = y ? slabL : slabR;
    int2* meta = y ? metaL : metaR;
    float* dis = y ? disL : disR;

    __shared__ unsigned int sin_[CAP];       // 36.9 KB (no sout -> 4 blocks/CU)
    __shared__ int hcnt[BNODES], hoff[BNODES], hcur[BNODES];
    __shared__ int wtot[4];
    __shared__ int totc;
    int t = threadIdx.x;
    int lane = t & 63, wave = t >> 6;
    int b = blockIdx.x;

    int a0 = offsTT[b * NCH + t],        e0 = offsTT[(b + 1) * NCH + t];
    int a1 = offsTT[b * NCH + t + 256],  e1 = offsTT[(b + 1) * NCH + t + 256];
    int len = (e0 - a0) + (e1 - a1);

    int x = len;
#pragma unroll
    for (int d0 = 1; d0 < 64; d0 <<= 1) {
        int yy = __shfl_up(x, d0, 64);
        if (lane >= d0) x += yy;
    }
    if (lane == 63) wtot[wave] = x;
    hcnt[t] = 0;
    __syncthreads();
    int pre = 0;
    for (int w2 = 0; w2 < wave; w2++) pre += wtot[w2];
    int sbase = x - len + pre;
    if (t == 255) totc = sbase + len;
    __syncthreads();

    int p = sbase;
    {
        int cb = t * ECHUNK;
        for (int i = (a0 & ~3); i < e0; i += 4) {
            uint4 v = *(const uint4*)(slabC + cb + i);
            unsigned int vv[4] = {v.x, v.y, v.z, v.w};
#pragma unroll
            for (int k = 0; k < 4; k++) {
                int idx = i + k;
                if (idx >= a0 && idx < e0) { if (p < CAP) sin_[p] = vv[k]; p++; }
            }
        }
        cb = (t + 256) * ECHUNK;
        for (int i = (a1 & ~3); i < e1; i += 4) {
            uint4 v = *(const uint4*)(slabC + cb + i);
            unsigned int vv[4] = {v.x, v.y, v.z, v.w};
#pragma unroll
            for (int k = 0; k < 4; k++) {
                int idx = i + k;
                if (idx >= a1 && idx < e1) { if (p < CAP) sin_[p] = vv[k]; p++; }
            }
        }
    }
    __syncthreads();
    int cnt = totc;
    if (cnt > CAP) cnt = CAP;

    for (int i = t; i < cnt; i += 256) atomicAdd(&hcnt[sin_[i] >> 18], 1);
    __syncthreads();

    int v2 = hcnt[t];
    int x2 = v2;
#pragma unroll
    for (int d0 = 1; d0 < 64; d0 <<= 1) {
        int yy = __shfl_up(x2, d0, 64);
        if (lane >= d0) x2 += yy;
    }
    if (lane == 63) wtot[wave] = x2;
    __syncthreads();
    int pre2 = 0;
    for (int w2 = 0; w2 < wave; w2++) pre2 += wtot[w2];
    int ex = x2 - v2 + pre2;
    hoff[t] = ex;
    hcur[t] = ex;
    __syncthreads();

    int gb = b * CAP;
    for (int i = t; i < cnt; i += 256) {
        unsigned int r = sin_[i];
        int pp = atomicAdd(&hcur[r >> 18], 1);
        if (pp < CAP) slab[gb + pp] = r & 0x3FFFFu;   // scattered within 36KB window
    }
    int node = (b << 8) + t;
    if (node < N_NODES) {
        meta[node] = make_int2(gb + hoff[t], gb + hoff[t] + hcnt[t]);
        dis[node] = rsqrtf((float)hcnt[t] + 1.0f);
    }
}

// ---- t1 (fused R+L): hs1[i,j] = bf16( (emb[ids[i]] @ W1)[j] * dis[i] ) ----
__global__ __launch_bounds__(256) void t1_kernel(
        const int* __restrict__ idsR, const int* __restrict__ idsL,
        const float* __restrict__ emb, const float* __restrict__ W,
        const float* __restrict__ disR, const float* __restrict__ disL,
        __hip_bfloat16* __restrict__ hsR, __hip_bfloat16* __restrict__ hsL) {
    int y = blockIdx.y;
    const int* ids = y ? idsL : idsR;
    const float* dis = y ? disL : disR;
    __hip_bfloat16* hs = y ? hsL : hsR;
    __shared__ float sW[D][D];
    __shared__ float sx[16][D + 1];
    int t = threadIdx.x;
    int j = t & 15, g = t >> 4;
    sW[g][j] = W[t];
    int i = (blockIdx.x << 4) + g;
    sx[g][j] = emb[(size_t)ids[i] * D + j];
    __syncthreads();
    float acc = 0.f;
#pragma unroll
    for (int k = 0; k < D; k++) acc += sx[g][k] * sW[k][j];
    hs[(size_t)i * D + j] = __float2bfloat16(acc * dis[i]);
}

// ---- G1: gather layer1 + relu + transform2 -> hs2. 32 nodes/block, 8 lanes/node.
//      protein = blockIdx.x & 1: round-robin XCD mapping puts R on even XCDs,
//      L on odd -> each XCD's L2 caches only one 6.4MB table ----
__global__ __launch_bounds__(256) void g1_kernel(
        const int2* __restrict__ metaR, const int2* __restrict__ metaL,
        const unsigned int* __restrict__ csrR, const unsigned int* __restrict__ csrL,
        const __hip_bfloat16* __restrict__ hs1R, const __hip_bfloat16* __restrict__ hs1L,
        const float* __restrict__ disR, const float* __restrict__ disL,
        const float* __restrict__ b1, const float* __restrict__ W2,
        __hip_bfloat16* __restrict__ hs2R, __hip_bfloat16* __restrict__ hs2L) {
    int half = blockIdx.x & 1;
    int bx = blockIdx.x >> 1;
    const int2* meta = half ? metaL : metaR;
    const unsigned int* csr = half ? csrL : csrR;
    const __hip_bfloat16* hs1 = half ? hs1L : hs1R;
    const float* dis = half ? disL : disR;
    __hip_bfloat16* hs2 = half ? hs2L : hs2R;

    __shared__ float sW[D][D];
    __shared__ float sx[32][D + 1];
    int t = threadIdx.x;
    int jp = t & 7, g = t >> 3;
    sW[t >> 4][t & 15] = W2[t];
    int i = (bx << 5) + g;
    int2 be = meta[i];
    float2 acc = __bfloat1622float2(
        *(const __hip_bfloat162*)(hs1 + (size_t)i * D + 2 * jp));
    int e = be.x, end = be.y;
    for (; e + 8 <= end; e += 8) {
        int my = (int)__builtin_nontemporal_load(csr + e + jp);
#pragma unroll
        for (int n = 0; n < 8; n++) {
            int s = __shfl(my, n, 8);
            float2 f = __bfloat1622float2(
                *(const __hip_bfloat162*)(hs1 + (size_t)s * D + 2 * jp));
            acc.x += f.x; acc.y += f.y;
        }
    }
    for (; e < end; e++) {
        int s = (int)__builtin_nontemporal_load(csr + e);
        float2 f = __bfloat1622float2(
            *(const __hip_bfloat162*)(hs1 + (size_t)s * D + 2 * jp));
        acc.x += f.x; acc.y += f.y;
    }
    float di = dis[i];
    sx[g][2 * jp]     = fmaxf(acc.x * di + b1[2 * jp], 0.f);
    sx[g][2 * jp + 1] = fmaxf(acc.y * di + b1[2 * jp + 1], 0.f);
    __syncthreads();
    float a0 = 0.f, a1 = 0.f;
#pragma unroll
    for (int k = 0; k < D; k++) {
        float xv = sx[g][k];
        a0 += xv * sW[k][2 * jp];
        a1 += xv * sW[k][2 * jp + 1];
    }
    *(__hip_bfloat162*)(hs2 + (size_t)i * D + 2 * jp) =
        __float22bfloat162_rn(make_float2(a0 * di, a1 * di));
}

// ---- G2: gather layer2 + fused mean-pool partial reduction (parity protein map) ----
__global__ __launch_bounds__(256) void g2_kernel(
        const int2* __restrict__ metaR, const int2* __restrict__ metaL,
        const unsigned int* __restrict__ csrR, const unsigned int* __restrict__ csrL,
        const __hip_bfloat16* __restrict__ hs2R, const __hip_bfloat16* __restrict__ hs2L,
        const float* __restrict__ disR, const float* __restrict__ disL,
        const float* __restrict__ b2,
        const int* __restrict__ batR, const int* __restrict__ batL,
        float* __restrict__ sumsR, float* __restrict__ sumsL,
        float* __restrict__ cntR, float* __restrict__ cntL) {
    int half = blockIdx.x & 1;
    int bx = blockIdx.x >> 1;
    const int2* meta = half ? metaL : metaR;
    const unsigned int* csr = half ? csrL : csrR;
    const __hip_bfloat16* hs2 = half ? hs2L : hs2R;
    const float* dis = half ? disL : disR;
    const int* batch = half ? batL : batR;
    float* sums = half ? sumsL : sumsR;
    float* cnt = half ? cntL : cntR;

    __shared__ float sv[32][D + 1];
    __shared__ int sb[32];
    int t = threadIdx.x;
    int jp = t & 7, g = t >> 3;
    int i = (bx << 5) + g;
    int2 be = meta[i];
    float2 acc = __bfloat1622float2(
        *(const __hip_bfloat162*)(hs2 + (size_t)i * D + 2 * jp));
    int e = be.x, end = be.y;
    for (; e + 8 <= end; e += 8) {
        int my = (int)__builtin_nontemporal_load(csr + e + jp);
#pragma unroll
        for (int n = 0; n < 8; n++) {
            int s = __shfl(my, n, 8);
            float2 f = __bfloat1622float2(
                *(const __hip_bfloat162*)(hs2 + (size_t)s * D + 2 * jp));
            acc.x += f.x; acc.y += f.y;
        }
    }
    for (; e < end; e++) {
        int s = (int)__builtin_nontemporal_load(csr + e);
        float2 f = __bfloat1622float2(
            *(const __hip_bfloat162*)(hs2 + (size_t)s * D + 2 * jp));
        acc.x += f.x; acc.y += f.y;
    }
    float di = dis[i];
    int bi = batch[i];
    sv[g][2 * jp]     = acc.x * di + b2[2 * jp];
    sv[g][2 * jp + 1] = acc.y * di + b2[2 * jp + 1];
    if (jp == 0) sb[g] = bi;
    __syncthreads();
    bool runend = (g == 31) || (sb[g + 1] != bi);
    if (runend) {
        float s0 = 0.f, s1 = 0.f;
        int gg = g;
        while (gg >= 0 && sb[gg] == bi) { s0 += sv[gg][2 * jp]; s1 += sv[gg][2 * jp + 1]; gg--; }
        atomicAdd(&sums[bi * D + 2 * jp], s0);
        atomicAdd(&sums[bi * D + 2 * jp + 1], s1);
        if (jp == 0) atomicAdd(&cnt[bi], (float)(g - gg));
    }
}

// ---- final FC ----
__global__ void final_kernel(const float* __restrict__ rs, const float* __restrict__ rc,
                             const float* __restrict__ ls, const float* __restrict__ lc,
                             const float* __restrict__ fcW, const float* __restrict__ fcb,
                             float* __restrict__ out) {
    int b = blockIdx.x * blockDim.x + threadIdx.x;
    if (b >= N_GRAPHS) return;
    float hc[2 * D];
    float rn = fmaxf(rc[b], 1.f), ln = fmaxf(lc[b], 1.f);
#pragma unroll
    for (int j = 0; j < D; j++) {
        hc[j]     = rs[b * D + j] / rn;
        hc[D + j] = ls[b * D + j] / ln;
    }
#pragma unroll
    for (int c = 0; c < 6; c++) {
        float acc = fcb[c];
#pragma unroll
        for (int j = 0; j < 2 * D; j++) acc += hc[j] * fcW[c * 2 * D + j];
        if (c < 3) out[b * 3 + c] = acc;
        else       out[N_GRAPHS * 3 + b * 3 + (c - 3)] = acc;
    }
}

extern "C" void kernel_launch(void* const* d_in, const int* in_sizes, int n_in,
                              void* d_out, int out_size, void* d_ws, size_t ws_size,
                              hipStream_t stream) {
    const float* emb = (const float*)d_in[0];
    const float* W1  = (const float*)d_in[1];
    const float* b1  = (const float*)d_in[2];
    const float* W2  = (const float*)d_in[3];
    const float* b2  = (const float*)d_in[4];
    const float* fcW = (const float*)d_in[5];
    const float* fcb = (const float*)d_in[6];
    const int* rx = (const int*)d_in[7];
    const int* re = (const int*)d_in[8];
    const int* rb = (const int*)d_in[9];
    const int* lx = (const int*)d_in[10];
    const int* le = (const int*)d_in[11];
    const int* lb = (const int*)d_in[12];
    float* out = (float*)d_out;

    char* w = (char*)d_ws;
    // slabC region (51.2 MB), dead after pB; bf16 hs arrays (25.6 MB) overlay it.
    unsigned int* slabC_R = (unsigned int*)w;
    __hip_bfloat16* hs1R = (__hip_bfloat16*)w;
    __hip_bfloat16* hs1L = hs1R + (size_t)N_NODES * D;
    __hip_bfloat16* hs2R = hs1L + (size_t)N_NODES * D;
    __hip_bfloat16* hs2L = hs2R + (size_t)N_NODES * D;
    w += (size_t)NEDGE * 4;
    unsigned int* slabC_L = (unsigned int*)w;  w += (size_t)NEDGE * 4;
    unsigned int* slabR = (unsigned int*)w;    w += (size_t)NBUK * CAP * 4;
    unsigned int* slabL = (unsigned int*)w;    w += (size_t)NBUK * CAP * 4;
    int* offsT_R = (int*)w;                    w += (size_t)NCH * OSTRIDE * 4;
    int* offsT_L = (int*)w;                    w += (size_t)NCH * OSTRIDE * 4;
    int* offsTT_R = (int*)w;                   w += (size_t)OSTRIDE * NCH * 4;
    int* offsTT_L = (int*)w;                   w += (size_t)OSTRIDE * NCH * 4;
    int2* metaR = (int2*)w;                    w += (size_t)N_NODES * 8;
    int2* metaL = (int2*)w;                    w += (size_t)N_NODES * 8;
    float* disR = (float*)w;                   w += (size_t)N_NODES * 4;
    float* disL = (float*)w;                   w += (size_t)N_NODES * 4;
    float* sums0 = (float*)w;                  w += (size_t)N_GRAPHS * D * 4;
    float* cnt0  = (float*)w;                  w += (size_t)N_GRAPHS * 4;
    float* sums1 = (float*)w;                  w += (size_t)N_GRAPHS * D * 4;
    float* cnt1  = (float*)w;                  w += (size_t)N_GRAPHS * 4;

    const int* srcR = re;  const int* dstR = re + NEDGE;
    const int* srcL = le;  const int* dstL = le + NEDGE;

    hipMemsetAsync(sums0, 0, ((size_t)N_GRAPHS * (D + 1)) * 2 * sizeof(float), stream);

    // ---- CSR build (R+L fused) ----
    pA<<<dim3(NCH, 2), 1024, 0, stream>>>(srcR, dstR, srcL, dstL,
                                          slabC_R, slabC_L, offsT_R, offsT_L);
    tr_kernel<<<dim3((OSTRIDE + 31) / 32, NCH / 32, 2), 256, 0, stream>>>(
        offsT_R, offsT_L, offsTT_R, offsTT_L);
    pB<<<dim3(NBUK, 2), 256, 0, stream>>>(slabC_R, slabC_L, offsTT_R, offsTT_L,
                                          slabR, slabL, metaR, metaL, disR, disL);

    // ---- fused GCN pipeline ----
    t1_kernel<<<dim3(GBLK, 2), 256, 0, stream>>>(rx, lx, emb, W1, disR, disL, hs1R, hs1L);
    g1_kernel<<<GBLK, 256, 0, stream>>>(metaR, metaL, slabR, slabL,
                                        hs1R, hs1L, disR, disL, b1, W2, hs2R, hs2L);
    g2_kernel<<<GBLK, 256, 0, stream>>>(metaR, metaL, slabR, slabL,
                                        hs2R, hs2L, disR, disL, b2, rb, lb,
                                        sums0, sums1, cnt0, cnt1);
    final_kernel<<<(N_GRAPHS + 255) / 256, 256, 0, stream>>>(
        sums0, cnt0, sums1, cnt1, fcW, fcb, out);
}

// Round 10
// 543.407 us; speedup vs baseline: 1.5932x; 1.0524x over previous
//
#include <hip/hip_runtime.h>
#include <hip/hip_bf16.h>

#define N_NODES 200000
#define N_GRAPHS 1024
#define D 16
#define NEDGE 6400000

#define BNODES 256                 // nodes per bucket: bucket = dst >> 8
#define NBUK 782                   // ceil(200000/256)
#define NCH 512                    // edge chunks
#define ECHUNK 12500               // NEDGE / NCH (exact)
#define EC4 (ECHUNK / 4)           // 3125 int4 groups (exact)
#define OSTRIDE (NBUK + 1)         // 783
#define CAP 9216                   // bucket slab capacity (mean 8192, sd ~90 -> 11 sigma)
#define GBLK 12500                 // t1 blocks: 16 nodes x 16 lanes
#define GHALF 6250                 // gather blocks per protein: 32 nodes x 8 lanes

// ---- pA (fused R+L): sort one 12500-edge chunk by bucket in LDS, coalesced writeback ----
__global__ __launch_bounds__(1024) void pA(
        const int* __restrict__ srcR, const int* __restrict__ dstR,
        const int* __restrict__ srcL, const int* __restrict__ dstL,
        unsigned int* __restrict__ slabC_R, unsigned int* __restrict__ slabC_L,
        int* __restrict__ offsT_R, int* __restrict__ offsT_L) {
    const int* src = blockIdx.y ? srcL : srcR;
    const int* dst = blockIdx.y ? dstL : dstR;
    unsigned int* slabC = blockIdx.y ? slabC_L : slabC_R;
    int* offsT = blockIdx.y ? offsT_L : offsT_R;

    __shared__ unsigned int stage[ECHUNK];   // 50 KB
    __shared__ int lh[NBUK];
    __shared__ int lcur[NBUK];
    __shared__ int wsum[16];
    int t = threadIdx.x;
    int wave = t >> 6, lane = t & 63;
    int c = blockIdx.x;
    int base = c * ECHUNK;                   // 50000 B offset: 16B-aligned for all c
    const int4* dst4 = (const int4*)(dst + base);
    const int4* src4 = (const int4*)(src + base);

    for (int k = t; k < NBUK; k += 1024) lh[k] = 0;
    __syncthreads();
    for (int i = t; i < EC4; i += 1024) {
        int4 d4 = dst4[i];
        atomicAdd(&lh[((unsigned int)d4.x) >> 8], 1);
        atomicAdd(&lh[((unsigned int)d4.y) >> 8], 1);
        atomicAdd(&lh[((unsigned int)d4.z) >> 8], 1);
        atomicAdd(&lh[((unsigned int)d4.w) >> 8], 1);
    }
    __syncthreads();

    int v = (t < NBUK) ? lh[t] : 0;
    int x = v;
#pragma unroll
    for (int d0 = 1; d0 < 64; d0 <<= 1) {
        int y = __shfl_up(x, d0, 64);
        if (lane >= d0) x += y;
    }
    if (lane == 63) wsum[wave] = x;
    __syncthreads();
    if (wave == 0 && lane < 16) {
        int s = wsum[lane];
#pragma unroll
        for (int d0 = 1; d0 < 16; d0 <<= 1) {
            int y = __shfl_up(s, d0, 64);
            if (lane >= d0) s += y;
        }
        wsum[lane] = s;
    }
    __syncthreads();
    int excl = x - v + (wave ? wsum[wave - 1] : 0);
    if (t < NBUK) lcur[t] = excl;
    __syncthreads();

    for (int i = t; i < EC4; i += 1024) {
        int4 d4 = dst4[i];
        int4 s4 = src4[i];
        int dd[4] = {d4.x, d4.y, d4.z, d4.w};
        int ss[4] = {s4.x, s4.y, s4.z, s4.w};
#pragma unroll
        for (int k = 0; k < 4; k++) {
            int pos = atomicAdd(&lcur[dd[k] >> 8], 1);
            stage[pos] = ((unsigned int)(dd[k] & 255) << 18) | (unsigned int)ss[k];
        }
    }
    __syncthreads();
    uint4* out4 = (uint4*)(slabC + base);
    const uint4* st4 = (const uint4*)stage;
    for (int i = t; i < EC4; i += 1024) out4[i] = st4[i];
    if (t < NBUK) offsT[c * OSTRIDE + t] = excl;
    if (t == 0) offsT[c * OSTRIDE + NBUK] = ECHUNK;
}

// ---- transpose offsT [NCH][OSTRIDE] -> offsTT [OSTRIDE][NCH] ----
__global__ __launch_bounds__(256) void tr_kernel(
        const int* __restrict__ offsT_R, const int* __restrict__ offsT_L,
        int* __restrict__ offsTT_R, int* __restrict__ offsTT_L) {
    const int* in = blockIdx.z ? offsT_L : offsT_R;
    int* outp = blockIdx.z ? offsTT_L : offsTT_R;
    __shared__ int tile[32][33];
    int lx = threadIdx.x & 31, ly = threadIdx.x >> 5;
#pragma unroll
    for (int r = 0; r < 32; r += 8) {
        int row = blockIdx.y * 32 + ly + r;
        int col = blockIdx.x * 32 + lx;
        if (col < OSTRIDE) tile[ly + r][lx] = in[row * OSTRIDE + col];
    }
    __syncthreads();
#pragma unroll
    for (int r = 0; r < 32; r += 8) {
        int orow = blockIdx.x * 32 + ly + r;
        int ocol = blockIdx.y * 32 + lx;
        if (orow < OSTRIDE) outp[orow * NCH + ocol] = tile[lx][ly + r];
    }
}

// ---- pB (fused R+L): single-pass counting sort; scattered 4B writes into the
//      bucket's dense 36KB global window (L2 merges into full lines) ----
__global__ __launch_bounds__(256) void pB(
        const unsigned int* __restrict__ slabC_R, const unsigned int* __restrict__ slabC_L,
        const int* __restrict__ offsTT_R, const int* __restrict__ offsTT_L,
        unsigned int* __restrict__ slabR, unsigned int* __restrict__ slabL,
        int2* __restrict__ metaR, int2* __restrict__ metaL,
        float* __restrict__ disR, float* __restrict__ disL) {
    int y = blockIdx.y;
    const unsigned int* slabC = y ? slabC_L : slabC_R;
    const int* offsTT = y ? offsTT_L : offsTT_R;
    unsigned int* slab = y ? slabL : slabR;
    int2* meta = y ? metaL : metaR;
    float* dis = y ? disL : disR;

    __shared__ unsigned int sin_[CAP];       // 36.9 KB (no sout -> better occupancy)
    __shared__ int hcnt[BNODES], hoff[BNODES], hcur[BNODES];
    __shared__ int wtot[4];
    __shared__ int totc;
    int t = threadIdx.x;
    int lane = t & 63, wave = t >> 6;
    int b = blockIdx.x;

    int a0 = offsTT[b * NCH + t],        e0 = offsTT[(b + 1) * NCH + t];
    int a1 = offsTT[b * NCH + t + 256],  e1 = offsTT[(b + 1) * NCH + t + 256];
    int len = (e0 - a0) + (e1 - a1);

    int x = len;
#pragma unroll
    for (int d0 = 1; d0 < 64; d0 <<= 1) {
        int yy = __shfl_up(x, d0, 64);
        if (lane >= d0) x += yy;
    }
    if (lane == 63) wtot[wave] = x;
    hcnt[t] = 0;
    __syncthreads();
    int pre = 0;
    for (int w2 = 0; w2 < wave; w2++) pre += wtot[w2];
    int sbase = x - len + pre;
    if (t == 255) totc = sbase + len;
    __syncthreads();

    int p = sbase;
    {
        int cb = t * ECHUNK;
        for (int i = (a0 & ~3); i < e0; i += 4) {
            uint4 v = *(const uint4*)(slabC + cb + i);
            unsigned int vv[4] = {v.x, v.y, v.z, v.w};
#pragma unroll
            for (int k = 0; k < 4; k++) {
                int idx = i + k;
                if (idx >= a0 && idx < e0) { if (p < CAP) sin_[p] = vv[k]; p++; }
            }
        }
        cb = (t + 256) * ECHUNK;
        for (int i = (a1 & ~3); i < e1; i += 4) {
            uint4 v = *(const uint4*)(slabC + cb + i);
            unsigned int vv[4] = {v.x, v.y, v.z, v.w};
#pragma unroll
            for (int k = 0; k < 4; k++) {
                int idx = i + k;
                if (idx >= a1 && idx < e1) { if (p < CAP) sin_[p] = vv[k]; p++; }
            }
        }
    }
    __syncthreads();
    int cnt = totc;
    if (cnt > CAP) cnt = CAP;

    for (int i = t; i < cnt; i += 256) atomicAdd(&hcnt[sin_[i] >> 18], 1);
    __syncthreads();

    int v2 = hcnt[t];
    int x2 = v2;
#pragma unroll
    for (int d0 = 1; d0 < 64; d0 <<= 1) {
        int yy = __shfl_up(x2, d0, 64);
        if (lane >= d0) x2 += yy;
    }
    if (lane == 63) wtot[wave] = x2;
    __syncthreads();
    int pre2 = 0;
    for (int w2 = 0; w2 < wave; w2++) pre2 += wtot[w2];
    int ex = x2 - v2 + pre2;
    hoff[t] = ex;
    hcur[t] = ex;
    __syncthreads();

    int gb = b * CAP;
    for (int i = t; i < cnt; i += 256) {
        unsigned int r = sin_[i];
        int pp = atomicAdd(&hcur[r >> 18], 1);
        if (pp < CAP) slab[gb + pp] = r & 0x3FFFFu;   // scattered within 36KB window
    }
    int node = (b << 8) + t;
    if (node < N_NODES) {
        meta[node] = make_int2(gb + hoff[t], gb + hoff[t] + hcnt[t]);
        dis[node] = rsqrtf((float)hcnt[t] + 1.0f);
    }
}

// ---- t1 (fused R+L): hs1[i,j] = bf16( (emb[ids[i]] @ W1)[j] * dis[i] ) ----
__global__ __launch_bounds__(256) void t1_kernel(
        const int* __restrict__ idsR, const int* __restrict__ idsL,
        const float* __restrict__ emb, const float* __restrict__ W,
        const float* __restrict__ disR, const float* __restrict__ disL,
        __hip_bfloat16* __restrict__ hsR, __hip_bfloat16* __restrict__ hsL) {
    int y = blockIdx.y;
    const int* ids = y ? idsL : idsR;
    const float* dis = y ? disL : disR;
    __hip_bfloat16* hs = y ? hsL : hsR;
    __shared__ float sW[D][D];
    __shared__ float sx[16][D + 1];
    int t = threadIdx.x;
    int j = t & 15, g = t >> 4;
    sW[g][j] = W[t];
    int i = (blockIdx.x << 4) + g;
    sx[g][j] = emb[(size_t)ids[i] * D + j];
    __syncthreads();
    float acc = 0.f;
#pragma unroll
    for (int k = 0; k < D; k++) acc += sx[g][k] * sW[k][j];
    hs[(size_t)i * D + j] = __float2bfloat16(acc * dis[i]);
}

// ---- G1: gather layer1 + relu + transform2 -> hs2. 32 nodes/block, 8 lanes/node.
//      grid.x = 2*GHALF; first half = R (temporal L2 separation, measured best) ----
__global__ __launch_bounds__(256) void g1_kernel(
        const int2* __restrict__ metaR, const int2* __restrict__ metaL,
        const unsigned int* __restrict__ csrR, const unsigned int* __restrict__ csrL,
        const __hip_bfloat16* __restrict__ hs1R, const __hip_bfloat16* __restrict__ hs1L,
        const float* __restrict__ disR, const float* __restrict__ disL,
        const float* __restrict__ b1, const float* __restrict__ W2,
        __hip_bfloat16* __restrict__ hs2R, __hip_bfloat16* __restrict__ hs2L) {
    int half = (blockIdx.x >= GHALF);
    int bx = blockIdx.x - (half ? GHALF : 0);
    const int2* meta = half ? metaL : metaR;
    const unsigned int* csr = half ? csrL : csrR;
    const __hip_bfloat16* hs1 = half ? hs1L : hs1R;
    const float* dis = half ? disL : disR;
    __hip_bfloat16* hs2 = half ? hs2L : hs2R;

    __shared__ float sW[D][D];
    __shared__ float sx[32][D + 1];
    int t = threadIdx.x;
    int jp = t & 7, g = t >> 3;
    sW[t >> 4][t & 15] = W2[t];
    int i = (bx << 5) + g;
    int2 be = meta[i];
    float2 acc = __bfloat1622float2(
        *(const __hip_bfloat162*)(hs1 + (size_t)i * D + 2 * jp));
    int e = be.x, end = be.y;
    for (; e + 8 <= end; e += 8) {
        int my = (int)csr[e + jp];
#pragma unroll
        for (int n = 0; n < 8; n++) {
            int s = __shfl(my, n, 8);
            float2 f = __bfloat1622float2(
                *(const __hip_bfloat162*)(hs1 + (size_t)s * D + 2 * jp));
            acc.x += f.x; acc.y += f.y;
        }
    }
    for (; e < end; e++) {
        int s = csr[e];
        float2 f = __bfloat1622float2(
            *(const __hip_bfloat162*)(hs1 + (size_t)s * D + 2 * jp));
        acc.x += f.x; acc.y += f.y;
    }
    float di = dis[i];
    sx[g][2 * jp]     = fmaxf(acc.x * di + b1[2 * jp], 0.f);
    sx[g][2 * jp + 1] = fmaxf(acc.y * di + b1[2 * jp + 1], 0.f);
    __syncthreads();
    float a0 = 0.f, a1 = 0.f;
#pragma unroll
    for (int k = 0; k < D; k++) {
        float xv = sx[g][k];
        a0 += xv * sW[k][2 * jp];
        a1 += xv * sW[k][2 * jp + 1];
    }
    *(__hip_bfloat162*)(hs2 + (size_t)i * D + 2 * jp) =
        __float22bfloat162_rn(make_float2(a0 * di, a1 * di));
}

// ---- G2: gather layer2 + fused mean-pool partial reduction ----
__global__ __launch_bounds__(256) void g2_kernel(
        const int2* __restrict__ metaR, const int2* __restrict__ metaL,
        const unsigned int* __restrict__ csrR, const unsigned int* __restrict__ csrL,
        const __hip_bfloat16* __restrict__ hs2R, const __hip_bfloat16* __restrict__ hs2L,
        const float* __restrict__ disR, const float* __restrict__ disL,
        const float* __restrict__ b2,
        const int* __restrict__ batR, const int* __restrict__ batL,
        float* __restrict__ sumsR, float* __restrict__ sumsL,
        float* __restrict__ cntR, float* __restrict__ cntL) {
    int half = (blockIdx.x >= GHALF);
    int bx = blockIdx.x - (half ? GHALF : 0);
    const int2* meta = half ? metaL : metaR;
    const unsigned int* csr = half ? csrL : csrR;
    const __hip_bfloat16* hs2 = half ? hs2L : hs2R;
    const float* dis = half ? disL : disR;
    const int* batch = half ? batL : batR;
    float* sums = half ? sumsL : sumsR;
    float* cnt = half ? cntL : cntR;

    __shared__ float sv[32][D + 1];
    __shared__ int sb[32];
    int t = threadIdx.x;
    int jp = t & 7, g = t >> 3;
    int i = (bx << 5) + g;
    int2 be = meta[i];
    float2 acc = __bfloat1622float2(
        *(const __hip_bfloat162*)(hs2 + (size_t)i * D + 2 * jp));
    int e = be.x, end = be.y;
    for (; e + 8 <= end; e += 8) {
        int my = (int)csr[e + jp];
#pragma unroll
        for (int n = 0; n < 8; n++) {
            int s = __shfl(my, n, 8);
            float2 f = __bfloat1622float2(
                *(const __hip_bfloat162*)(hs2 + (size_t)s * D + 2 * jp));
            acc.x += f.x; acc.y += f.y;
        }
    }
    for (; e < end; e++) {
        int s = csr[e];
        float2 f = __bfloat1622float2(
            *(const __hip_bfloat162*)(hs2 + (size_t)s * D + 2 * jp));
        acc.x += f.x; acc.y += f.y;
    }
    float di = dis[i];
    int bi = batch[i];
    sv[g][2 * jp]     = acc.x * di + b2[2 * jp];
    sv[g][2 * jp + 1] = acc.y * di + b2[2 * jp + 1];
    if (jp == 0) sb[g] = bi;
    __syncthreads();
    bool runend = (g == 31) || (sb[g + 1] != bi);
    if (runend) {
        float s0 = 0.f, s1 = 0.f;
        int gg = g;
        while (gg >= 0 && sb[gg] == bi) { s0 += sv[gg][2 * jp]; s1 += sv[gg][2 * jp + 1]; gg--; }
        atomicAdd(&sums[bi * D + 2 * jp], s0);
        atomicAdd(&sums[bi * D + 2 * jp + 1], s1);
        if (jp == 0) atomicAdd(&cnt[bi], (float)(g - gg));
    }
}

// ---- final FC ----
__global__ void final_kernel(const float* __restrict__ rs, const float* __restrict__ rc,
                             const float* __restrict__ ls, const float* __restrict__ lc,
                             const float* __restrict__ fcW, const float* __restrict__ fcb,
                             float* __restrict__ out) {
    int b = blockIdx.x * blockDim.x + threadIdx.x;
    if (b >= N_GRAPHS) return;
    float hc[2 * D];
    float rn = fmaxf(rc[b], 1.f), ln = fmaxf(lc[b], 1.f);
#pragma unroll
    for (int j = 0; j < D; j++) {
        hc[j]     = rs[b * D + j] / rn;
        hc[D + j] = ls[b * D + j] / ln;
    }
#pragma unroll
    for (int c = 0; c < 6; c++) {
        float acc = fcb[c];
#pragma unroll
        for (int j = 0; j < 2 * D; j++) acc += hc[j] * fcW[c * 2 * D + j];
        if (c < 3) out[b * 3 + c] = acc;
        else       out[N_GRAPHS * 3 + b * 3 + (c - 3)] = acc;
    }
}

extern "C" void kernel_launch(void* const* d_in, const int* in_sizes, int n_in,
                              void* d_out, int out_size, void* d_ws, size_t ws_size,
                              hipStream_t stream) {
    const float* emb = (const float*)d_in[0];
    const float* W1  = (const float*)d_in[1];
    const float* b1  = (const float*)d_in[2];
    const float* W2  = (const float*)d_in[3];
    const float* b2  = (const float*)d_in[4];
    const float* fcW = (const float*)d_in[5];
    const float* fcb = (const float*)d_in[6];
    const int* rx = (const int*)d_in[7];
    const int* re = (const int*)d_in[8];
    const int* rb = (const int*)d_in[9];
    const int* lx = (const int*)d_in[10];
    const int* le = (const int*)d_in[11];
    const int* lb = (const int*)d_in[12];
    float* out = (float*)d_out;

    char* w = (char*)d_ws;
    // slabC region (51.2 MB), dead after pB; bf16 hs arrays (25.6 MB) overlay it.
    unsigned int* slabC_R = (unsigned int*)w;
    __hip_bfloat16* hs1R = (__hip_bfloat16*)w;
    __hip_bfloat16* hs1L = hs1R + (size_t)N_NODES * D;
    __hip_bfloat16* hs2R = hs1L + (size_t)N_NODES * D;
    __hip_bfloat16* hs2L = hs2R + (size_t)N_NODES * D;
    w += (size_t)NEDGE * 4;
    unsigned int* slabC_L = (unsigned int*)w;  w += (size_t)NEDGE * 4;
    unsigned int* slabR = (unsigned int*)w;    w += (size_t)NBUK * CAP * 4;
    unsigned int* slabL = (unsigned int*)w;    w += (size_t)NBUK * CAP * 4;
    int* offsT_R = (int*)w;                    w += (size_t)NCH * OSTRIDE * 4;
    int* offsT_L = (int*)w;                    w += (size_t)NCH * OSTRIDE * 4;
    int* offsTT_R = (int*)w;                   w += (size_t)OSTRIDE * NCH * 4;
    int* offsTT_L = (int*)w;                   w += (size_t)OSTRIDE * NCH * 4;
    int2* metaR = (int2*)w;                    w += (size_t)N_NODES * 8;
    int2* metaL = (int2*)w;                    w += (size_t)N_NODES * 8;
    float* disR = (float*)w;                   w += (size_t)N_NODES * 4;
    float* disL = (float*)w;                   w += (size_t)N_NODES * 4;
    float* sums0 = (float*)w;                  w += (size_t)N_GRAPHS * D * 4;
    float* cnt0  = (float*)w;                  w += (size_t)N_GRAPHS * 4;
    float* sums1 = (float*)w;                  w += (size_t)N_GRAPHS * D * 4;
    float* cnt1  = (float*)w;                  w += (size_t)N_GRAPHS * 4;

    const int* srcR = re;  const int* dstR = re + NEDGE;
    const int* srcL = le;  const int* dstL = le + NEDGE;

    hipMemsetAsync(sums0, 0, ((size_t)N_GRAPHS * (D + 1)) * 2 * sizeof(float), stream);

    // ---- CSR build (R+L fused) ----
    pA<<<dim3(NCH, 2), 1024, 0, stream>>>(srcR, dstR, srcL, dstL,
                                          slabC_R, slabC_L, offsT_R, offsT_L);
    tr_kernel<<<dim3((OSTRIDE + 31) / 32, NCH / 32, 2), 256, 0, stream>>>(
        offsT_R, offsT_L, offsTT_R, offsTT_L);
    pB<<<dim3(NBUK, 2), 256, 0, stream>>>(slabC_R, slabC_L, offsTT_R, offsTT_L,
                                          slabR, slabL, metaR, metaL, disR, disL);

    // ---- fused GCN pipeline ----
    t1_kernel<<<dim3(GBLK, 2), 256, 0, stream>>>(rx, lx, emb, W1, disR, disL, hs1R, hs1L);
    g1_kernel<<<2 * GHALF, 256, 0, stream>>>(metaR, metaL, slabR, slabL,
                                             hs1R, hs1L, disR, disL, b1, W2, hs2R, hs2L);
    g2_kernel<<<2 * GHALF, 256, 0, stream>>>(metaR, metaL, slabR, slabL,
                                             hs2R, hs2L, disR, disL, b2, rb, lb,
                                             sums0, sums1, cnt0, cnt1);
    final_kernel<<<(N_GRAPHS + 255) / 256, 256, 0, stream>>>(
        sums0, cnt0, sums1, cnt1, fcW, fcb, out);
}

// Round 11
// 540.205 us; speedup vs baseline: 1.6026x; 1.0059x over previous
//
#include <hip/hip_runtime.h>
#include <hip/hip_bf16.h>

#define N_NODES 200000
#define N_GRAPHS 1024
#define D 16
#define NEDGE 6400000
#define SPLIT 100000               // src-range split: lo table = 3.2 MB, fits 4MB XCD L2

#define BNODES 256                 // nodes per bucket: bucket = dst >> 8
#define NBUK 782                   // ceil(200000/256)
#define NCH 512                    // edge chunks
#define ECHUNK 12500               // NEDGE / NCH (exact)
#define EC4 (ECHUNK / 4)           // 3125 int4 groups (exact)
#define OSTRIDE (NBUK + 1)         // 783
#define CAP 9216                   // bucket slab capacity (mean 8192, sd ~90 -> 11 sigma)
#define GBLK 12500                 // t1 blocks: 16 nodes x 16 lanes
#define GHALF 6250                 // gather blocks per protein: 32 nodes x 8 lanes

// ---- pA (fused R+L): sort one 12500-edge chunk by bucket in LDS, coalesced writeback ----
__global__ __launch_bounds__(1024) void pA(
        const int* __restrict__ srcR, const int* __restrict__ dstR,
        const int* __restrict__ srcL, const int* __restrict__ dstL,
        unsigned int* __restrict__ slabC_R, unsigned int* __restrict__ slabC_L,
        int* __restrict__ offsT_R, int* __restrict__ offsT_L) {
    const int* src = blockIdx.y ? srcL : srcR;
    const int* dst = blockIdx.y ? dstL : dstR;
    unsigned int* slabC = blockIdx.y ? slabC_L : slabC_R;
    int* offsT = blockIdx.y ? offsT_L : offsT_R;

    __shared__ unsigned int stage[ECHUNK];   // 50 KB
    __shared__ int lh[NBUK];
    __shared__ int lcur[NBUK];
    __shared__ int wsum[16];
    int t = threadIdx.x;
    int wave = t >> 6, lane = t & 63;
    int c = blockIdx.x;
    int base = c * ECHUNK;
    const int4* dst4 = (const int4*)(dst + base);
    const int4* src4 = (const int4*)(src + base);

    for (int k = t; k < NBUK; k += 1024) lh[k] = 0;
    __syncthreads();
    for (int i = t; i < EC4; i += 1024) {
        int4 d4 = dst4[i];
        atomicAdd(&lh[((unsigned int)d4.x) >> 8], 1);
        atomicAdd(&lh[((unsigned int)d4.y) >> 8], 1);
        atomicAdd(&lh[((unsigned int)d4.z) >> 8], 1);
        atomicAdd(&lh[((unsigned int)d4.w) >> 8], 1);
    }
    __syncthreads();

    int v = (t < NBUK) ? lh[t] : 0;
    int x = v;
#pragma unroll
    for (int d0 = 1; d0 < 64; d0 <<= 1) {
        int y = __shfl_up(x, d0, 64);
        if (lane >= d0) x += y;
    }
    if (lane == 63) wsum[wave] = x;
    __syncthreads();
    if (wave == 0 && lane < 16) {
        int s = wsum[lane];
#pragma unroll
        for (int d0 = 1; d0 < 16; d0 <<= 1) {
            int y = __shfl_up(s, d0, 64);
            if (lane >= d0) s += y;
        }
        wsum[lane] = s;
    }
    __syncthreads();
    int excl = x - v + (wave ? wsum[wave - 1] : 0);
    if (t < NBUK) lcur[t] = excl;
    __syncthreads();

    for (int i = t; i < EC4; i += 1024) {
        int4 d4 = dst4[i];
        int4 s4 = src4[i];
        int dd[4] = {d4.x, d4.y, d4.z, d4.w};
        int ss[4] = {s4.x, s4.y, s4.z, s4.w};
#pragma unroll
        for (int k = 0; k < 4; k++) {
            int pos = atomicAdd(&lcur[dd[k] >> 8], 1);
            stage[pos] = ((unsigned int)(dd[k] & 255) << 18) | (unsigned int)ss[k];
        }
    }
    __syncthreads();
    uint4* out4 = (uint4*)(slabC + base);
    const uint4* st4 = (const uint4*)stage;
    for (int i = t; i < EC4; i += 1024) out4[i] = st4[i];
    if (t < NBUK) offsT[c * OSTRIDE + t] = excl;
    if (t == 0) offsT[c * OSTRIDE + NBUK] = ECHUNK;
}

// ---- transpose offsT [NCH][OSTRIDE] -> offsTT [OSTRIDE][NCH] ----
__global__ __launch_bounds__(256) void tr_kernel(
        const int* __restrict__ offsT_R, const int* __restrict__ offsT_L,
        int* __restrict__ offsTT_R, int* __restrict__ offsTT_L) {
    const int* in = blockIdx.z ? offsT_L : offsT_R;
    int* outp = blockIdx.z ? offsTT_L : offsTT_R;
    __shared__ int tile[32][33];
    int lx = threadIdx.x & 31, ly = threadIdx.x >> 5;
#pragma unroll
    for (int r = 0; r < 32; r += 8) {
        int row = blockIdx.y * 32 + ly + r;
        int col = blockIdx.x * 32 + lx;
        if (col < OSTRIDE) tile[ly + r][lx] = in[row * OSTRIDE + col];
    }
    __syncthreads();
#pragma unroll
    for (int r = 0; r < 32; r += 8) {
        int orow = blockIdx.x * 32 + ly + r;
        int ocol = blockIdx.y * 32 + lx;
        if (orow < OSTRIDE) outp[orow * NCH + ocol] = tile[lx][ly + r];
    }
}

// ---- pB (fused R+L): single-pass 9-bit counting sort (key = local<<1 | srcHi).
//      Each node's run becomes [lo-src edges | hi-src edges]; meta = (beg, mid, end) ----
__global__ __launch_bounds__(256) void pB(
        const unsigned int* __restrict__ slabC_R, const unsigned int* __restrict__ slabC_L,
        const int* __restrict__ offsTT_R, const int* __restrict__ offsTT_L,
        unsigned int* __restrict__ slabR, unsigned int* __restrict__ slabL,
        int4* __restrict__ metaR, int4* __restrict__ metaL,
        float* __restrict__ disR, float* __restrict__ disL) {
    int y = blockIdx.y;
    const unsigned int* slabC = y ? slabC_L : slabC_R;
    const int* offsTT = y ? offsTT_L : offsTT_R;
    unsigned int* slab = y ? slabL : slabR;
    int4* meta = y ? metaL : metaR;
    float* dis = y ? disL : disR;

    __shared__ unsigned int sin_[CAP];       // 36.9 KB
    __shared__ int hcnt[2 * BNODES], hcur[2 * BNODES];
    __shared__ int wtot[4];
    __shared__ int totc;
    int t = threadIdx.x;
    int lane = t & 63, wave = t >> 6;
    int b = blockIdx.x;

    int a0 = offsTT[b * NCH + t],        e0 = offsTT[(b + 1) * NCH + t];
    int a1 = offsTT[b * NCH + t + 256],  e1 = offsTT[(b + 1) * NCH + t + 256];
    int len = (e0 - a0) + (e1 - a1);

    int x = len;
#pragma unroll
    for (int d0 = 1; d0 < 64; d0 <<= 1) {
        int yy = __shfl_up(x, d0, 64);
        if (lane >= d0) x += yy;
    }
    if (lane == 63) wtot[wave] = x;
    hcnt[2 * t] = 0;
    hcnt[2 * t + 1] = 0;
    __syncthreads();
    int pre = 0;
    for (int w2 = 0; w2 < wave; w2++) pre += wtot[w2];
    int sbase = x - len + pre;
    if (t == 255) totc = sbase + len;
    __syncthreads();

    int p = sbase;
    {
        int cb = t * ECHUNK;
        for (int i = (a0 & ~3); i < e0; i += 4) {
            uint4 v = *(const uint4*)(slabC + cb + i);
            unsigned int vv[4] = {v.x, v.y, v.z, v.w};
#pragma unroll
            for (int k = 0; k < 4; k++) {
                int idx = i + k;
                if (idx >= a0 && idx < e0) { if (p < CAP) sin_[p] = vv[k]; p++; }
            }
        }
        cb = (t + 256) * ECHUNK;
        for (int i = (a1 & ~3); i < e1; i += 4) {
            uint4 v = *(const uint4*)(slabC + cb + i);
            unsigned int vv[4] = {v.x, v.y, v.z, v.w};
#pragma unroll
            for (int k = 0; k < 4; k++) {
                int idx = i + k;
                if (idx >= a1 && idx < e1) { if (p < CAP) sin_[p] = vv[k]; p++; }
            }
        }
    }
    __syncthreads();
    int cnt = totc;
    if (cnt > CAP) cnt = CAP;

    for (int i = t; i < cnt; i += 256) {
        unsigned int r = sin_[i];
        int key = (int)((r >> 18) << 1) | (int)((r & 0x3FFFFu) >= (unsigned)SPLIT);
        atomicAdd(&hcnt[key], 1);
    }
    __syncthreads();

    int v0 = hcnt[2 * t], v1 = hcnt[2 * t + 1];
    int len2 = v0 + v1;
    int x2 = len2;
#pragma unroll
    for (int d0 = 1; d0 < 64; d0 <<= 1) {
        int yy = __shfl_up(x2, d0, 64);
        if (lane >= d0) x2 += yy;
    }
    if (lane == 63) wtot[wave] = x2;
    __syncthreads();
    int pre2 = 0;
    for (int w2 = 0; w2 < wave; w2++) pre2 += wtot[w2];
    int ex = x2 - len2 + pre2;
    hcur[2 * t] = ex;
    hcur[2 * t + 1] = ex + v0;
    __syncthreads();

    int gb = b * CAP;
    for (int i = t; i < cnt; i += 256) {
        unsigned int r = sin_[i];
        int key = (int)((r >> 18) << 1) | (int)((r & 0x3FFFFu) >= (unsigned)SPLIT);
        int pp = atomicAdd(&hcur[key], 1);
        if (pp < CAP) slab[gb + pp] = r & 0x3FFFFu;
    }
    int node = (b << 8) + t;
    if (node < N_NODES) {
        meta[node] = make_int4(gb + ex, gb + ex + v0, gb + ex + v0 + v1, 0);
        dis[node] = rsqrtf((float)(v0 + v1) + 1.0f);
    }
}

// ---- t1 (fused R+L): hs1[i,j] = bf16( (emb[ids[i]] @ W1)[j] * dis[i] ) ----
__global__ __launch_bounds__(256) void t1_kernel(
        const int* __restrict__ idsR, const int* __restrict__ idsL,
        const float* __restrict__ emb, const float* __restrict__ W,
        const float* __restrict__ disR, const float* __restrict__ disL,
        __hip_bfloat16* __restrict__ hsR, __hip_bfloat16* __restrict__ hsL) {
    int y = blockIdx.y;
    const int* ids = y ? idsL : idsR;
    const float* dis = y ? disL : disR;
    __hip_bfloat16* hs = y ? hsL : hsR;
    __shared__ float sW[D][D];
    __shared__ float sx[16][D + 1];
    int t = threadIdx.x;
    int j = t & 15, g = t >> 4;
    sW[g][j] = W[t];
    int i = (blockIdx.x << 4) + g;
    sx[g][j] = emb[(size_t)ids[i] * D + j];
    __syncthreads();
    float acc = 0.f;
#pragma unroll
    for (int k = 0; k < D; k++) acc += sx[g][k] * sW[k][j];
    hs[(size_t)i * D + j] = __float2bfloat16(acc * dis[i]);
}

// ---- gather pass A (lo sources, [beg, mid)): partial fp32 sums; self if i<SPLIT.
//      grid-half R/L temporal separation; lo table = 3.2MB, fits XCD L2 ----
__global__ __launch_bounds__(256) void ga_kernel(
        const int4* __restrict__ metaR, const int4* __restrict__ metaL,
        const unsigned int* __restrict__ csrR, const unsigned int* __restrict__ csrL,
        const __hip_bfloat16* __restrict__ hsR, const __hip_bfloat16* __restrict__ hsL,
        float2* __restrict__ partR, float2* __restrict__ partL) {
    int half = (blockIdx.x >= GHALF);
    int bx = blockIdx.x - (half ? GHALF : 0);
    const int4* meta = half ? metaL : metaR;
    const unsigned int* csr = half ? csrL : csrR;
    const __hip_bfloat16* hs = half ? hsL : hsR;
    float2* part = half ? partL : partR;

    int t = threadIdx.x;
    int jp = t & 7, g = t >> 3;
    int i = (bx << 5) + g;
    int4 be = meta[i];
    float2 acc = make_float2(0.f, 0.f);
    if (i < SPLIT) {
        acc = __bfloat1622float2(*(const __hip_bfloat162*)(hs + (size_t)i * D + 2 * jp));
    }
    int e = be.x, end = be.y;
    for (; e + 8 <= end; e += 8) {
        int my = (int)csr[e + jp];
#pragma unroll
        for (int n = 0; n < 8; n++) {
            int s = __shfl(my, n, 8);
            float2 f = __bfloat1622float2(
                *(const __hip_bfloat162*)(hs + (size_t)s * D + 2 * jp));
            acc.x += f.x; acc.y += f.y;
        }
    }
    for (; e < end; e++) {
        int s = (int)csr[e];
        float2 f = __bfloat1622float2(
            *(const __hip_bfloat162*)(hs + (size_t)s * D + 2 * jp));
        acc.x += f.x; acc.y += f.y;
    }
    part[(size_t)i * 8 + jp] = acc;
}

// ---- g1 pass B (hi sources, [mid, end)) + relu + transform2 -> hs2 ----
__global__ __launch_bounds__(256) void g1b_kernel(
        const int4* __restrict__ metaR, const int4* __restrict__ metaL,
        const unsigned int* __restrict__ csrR, const unsigned int* __restrict__ csrL,
        const __hip_bfloat16* __restrict__ hs1R, const __hip_bfloat16* __restrict__ hs1L,
        const float* __restrict__ disR, const float* __restrict__ disL,
        const float* __restrict__ b1, const float* __restrict__ W2,
        const float2* __restrict__ partR, const float2* __restrict__ partL,
        __hip_bfloat16* __restrict__ hs2R, __hip_bfloat16* __restrict__ hs2L) {
    int half = (blockIdx.x >= GHALF);
    int bx = blockIdx.x - (half ? GHALF : 0);
    const int4* meta = half ? metaL : metaR;
    const unsigned int* csr = half ? csrL : csrR;
    const __hip_bfloat16* hs1 = half ? hs1L : hs1R;
    const float* dis = half ? disL : disR;
    const float2* part = half ? partL : partR;
    __hip_bfloat16* hs2 = half ? hs2L : hs2R;

    __shared__ float sW[D][D];
    __shared__ float sx[32][D + 1];
    int t = threadIdx.x;
    int jp = t & 7, g = t >> 3;
    sW[t >> 4][t & 15] = W2[t];
    int i = (bx << 5) + g;
    int4 be = meta[i];
    float2 acc = part[(size_t)i * 8 + jp];
    if (i >= SPLIT) {
        float2 f = __bfloat1622float2(*(const __hip_bfloat162*)(hs1 + (size_t)i * D + 2 * jp));
        acc.x += f.x; acc.y += f.y;
    }
    int e = be.y, end = be.z;
    for (; e + 8 <= end; e += 8) {
        int my = (int)csr[e + jp];
#pragma unroll
        for (int n = 0; n < 8; n++) {
            int s = __shfl(my, n, 8);
            float2 f = __bfloat1622float2(
                *(const __hip_bfloat162*)(hs1 + (size_t)s * D + 2 * jp));
            acc.x += f.x; acc.y += f.y;
        }
    }
    for (; e < end; e++) {
        int s = (int)csr[e];
        float2 f = __bfloat1622float2(
            *(const __hip_bfloat162*)(hs1 + (size_t)s * D + 2 * jp));
        acc.x += f.x; acc.y += f.y;
    }
    float di = dis[i];
    sx[g][2 * jp]     = fmaxf(acc.x * di + b1[2 * jp], 0.f);
    sx[g][2 * jp + 1] = fmaxf(acc.y * di + b1[2 * jp + 1], 0.f);
    __syncthreads();
    float a0 = 0.f, a1 = 0.f;
#pragma unroll
    for (int k = 0; k < D; k++) {
        float xv = sx[g][k];
        a0 += xv * sW[k][2 * jp];
        a1 += xv * sW[k][2 * jp + 1];
    }
    *(__hip_bfloat162*)(hs2 + (size_t)i * D + 2 * jp) =
        __float22bfloat162_rn(make_float2(a0 * di, a1 * di));
}

// ---- g2 pass B (hi sources) + bias + fused mean-pool partial reduction ----
__global__ __launch_bounds__(256) void g2b_kernel(
        const int4* __restrict__ metaR, const int4* __restrict__ metaL,
        const unsigned int* __restrict__ csrR, const unsigned int* __restrict__ csrL,
        const __hip_bfloat16* __restrict__ hs2R, const __hip_bfloat16* __restrict__ hs2L,
        const float* __restrict__ disR, const float* __restrict__ disL,
        const float* __restrict__ b2,
        const int* __restrict__ batR, const int* __restrict__ batL,
        const float2* __restrict__ partR, const float2* __restrict__ partL,
        float* __restrict__ sumsR, float* __restrict__ sumsL,
        float* __restrict__ cntR, float* __restrict__ cntL) {
    int half = (blockIdx.x >= GHALF);
    int bx = blockIdx.x - (half ? GHALF : 0);
    const int4* meta = half ? metaL : metaR;
    const unsigned int* csr = half ? csrL : csrR;
    const __hip_bfloat16* hs2 = half ? hs2L : hs2R;
    const float* dis = half ? disL : disR;
    const int* batch = half ? batL : batR;
    const float2* part = half ? partL : partR;
    float* sums = half ? sumsL : sumsR;
    float* cnt = half ? cntL : cntR;

    __shared__ float sv[32][D + 1];
    __shared__ int sb[32];
    int t = threadIdx.x;
    int jp = t & 7, g = t >> 3;
    int i = (bx << 5) + g;
    int4 be = meta[i];
    float2 acc = part[(size_t)i * 8 + jp];
    if (i >= SPLIT) {
        float2 f = __bfloat1622float2(*(const __hip_bfloat162*)(hs2 + (size_t)i * D + 2 * jp));
        acc.x += f.x; acc.y += f.y;
    }
    int e = be.y, end = be.z;
    for (; e + 8 <= end; e += 8) {
        int my = (int)csr[e + jp];
#pragma unroll
        for (int n = 0; n < 8; n++) {
            int s = __shfl(my, n, 8);
            float2 f = __bfloat1622float2(
                *(const __hip_bfloat162*)(hs2 + (size_t)s * D + 2 * jp));
            acc.x += f.x; acc.y += f.y;
        }
    }
    for (; e < end; e++) {
        int s = (int)csr[e];
        float2 f = __bfloat1622float2(
            *(const __hip_bfloat162*)(hs2 + (size_t)s * D + 2 * jp));
        acc.x += f.x; acc.y += f.y;
    }
    float di = dis[i];
    int bi = batch[i];
    sv[g][2 * jp]     = acc.x * di + b2[2 * jp];
    sv[g][2 * jp + 1] = acc.y * di + b2[2 * jp + 1];
    if (jp == 0) sb[g] = bi;
    __syncthreads();
    bool runend = (g == 31) || (sb[g + 1] != bi);
    if (runend) {
        float s0 = 0.f, s1 = 0.f;
        int gg = g;
        while (gg >= 0 && sb[gg] == bi) { s0 += sv[gg][2 * jp]; s1 += sv[gg][2 * jp + 1]; gg--; }
        atomicAdd(&sums[bi * D + 2 * jp], s0);
        atomicAdd(&sums[bi * D + 2 * jp + 1], s1);
        if (jp == 0) atomicAdd(&cnt[bi], (float)(g - gg));
    }
}

// ---- final FC ----
__global__ void final_kernel(const float* __restrict__ rs, const float* __restrict__ rc,
                             const float* __restrict__ ls, const float* __restrict__ lc,
                             const float* __restrict__ fcW, const float* __restrict__ fcb,
                             float* __restrict__ out) {
    int b = blockIdx.x * blockDim.x + threadIdx.x;
    if (b >= N_GRAPHS) return;
    float hc[2 * D];
    float rn = fmaxf(rc[b], 1.f), ln = fmaxf(lc[b], 1.f);
#pragma unroll
    for (int j = 0; j < D; j++) {
        hc[j]     = rs[b * D + j] / rn;
        hc[D + j] = ls[b * D + j] / ln;
    }
#pragma unroll
    for (int c = 0; c < 6; c++) {
        float acc = fcb[c];
#pragma unroll
        for (int j = 0; j < 2 * D; j++) acc += hc[j] * fcW[c * 2 * D + j];
        if (c < 3) out[b * 3 + c] = acc;
        else       out[N_GRAPHS * 3 + b * 3 + (c - 3)] = acc;
    }
}

extern "C" void kernel_launch(void* const* d_in, const int* in_sizes, int n_in,
                              void* d_out, int out_size, void* d_ws, size_t ws_size,
                              hipStream_t stream) {
    const float* emb = (const float*)d_in[0];
    const float* W1  = (const float*)d_in[1];
    const float* b1  = (const float*)d_in[2];
    const float* W2  = (const float*)d_in[3];
    const float* b2  = (const float*)d_in[4];
    const float* fcW = (const float*)d_in[5];
    const float* fcb = (const float*)d_in[6];
    const int* rx = (const int*)d_in[7];
    const int* re = (const int*)d_in[8];
    const int* rb = (const int*)d_in[9];
    const int* lx = (const int*)d_in[10];
    const int* le = (const int*)d_in[11];
    const int* lb = (const int*)d_in[12];
    float* out = (float*)d_out;

    char* w = (char*)d_ws;
    // slabC_R region (25.6 MB), dead after pB; bf16 hs arrays (25.6 MB) overlay it.
    unsigned int* slabC_R = (unsigned int*)w;
    __hip_bfloat16* hs1R = (__hip_bfloat16*)w;
    __hip_bfloat16* hs1L = hs1R + (size_t)N_NODES * D;
    __hip_bfloat16* hs2R = hs1L + (size_t)N_NODES * D;
    __hip_bfloat16* hs2L = hs2R + (size_t)N_NODES * D;
    w += (size_t)NEDGE * 4;
    // slabC_L region (25.6 MB), dead after pB; fp32 gather partials (25.6 MB) overlay it.
    unsigned int* slabC_L = (unsigned int*)w;
    float2* partR = (float2*)slabC_L;
    float2* partL = partR + (size_t)N_NODES * 8;
    w += (size_t)NEDGE * 4;
    unsigned int* slabR = (unsigned int*)w;    w += (size_t)NBUK * CAP * 4;
    unsigned int* slabL = (unsigned int*)w;    w += (size_t)NBUK * CAP * 4;
    int* offsT_R = (int*)w;                    w += (size_t)NCH * OSTRIDE * 4;
    int* offsT_L = (int*)w;                    w += (size_t)NCH * OSTRIDE * 4;
    int* offsTT_R = (int*)w;                   w += (size_t)OSTRIDE * NCH * 4;
    int* offsTT_L = (int*)w;                   w += (size_t)OSTRIDE * NCH * 4;
    int4* metaR = (int4*)w;                    w += (size_t)N_NODES * 16;
    int4* metaL = (int4*)w;                    w += (size_t)N_NODES * 16;
    float* disR = (float*)w;                   w += (size_t)N_NODES * 4;
    float* disL = (float*)w;                   w += (size_t)N_NODES * 4;
    float* sums0 = (float*)w;                  w += (size_t)N_GRAPHS * D * 4;
    float* cnt0  = (float*)w;                  w += (size_t)N_GRAPHS * 4;
    float* sums1 = (float*)w;                  w += (size_t)N_GRAPHS * D * 4;
    float* cnt1  = (float*)w;                  w += (size_t)N_GRAPHS * 4;

    const int* srcR = re;  const int* dstR = re + NEDGE;
    const int* srcL = le;  const int* dstL = le + NEDGE;

    hipMemsetAsync(sums0, 0, ((size_t)N_GRAPHS * (D + 1)) * 2 * sizeof(float), stream);

    // ---- CSR build (R+L fused) ----
    pA<<<dim3(NCH, 2), 1024, 0, stream>>>(srcR, dstR, srcL, dstL,
                                          slabC_R, slabC_L, offsT_R, offsT_L);
    tr_kernel<<<dim3((OSTRIDE + 31) / 32, NCH / 32, 2), 256, 0, stream>>>(
        offsT_R, offsT_L, offsTT_R, offsTT_L);
    pB<<<dim3(NBUK, 2), 256, 0, stream>>>(slabC_R, slabC_L, offsTT_R, offsTT_L,
                                          slabR, slabL, metaR, metaL, disR, disL);

    // ---- fused GCN pipeline, two-phase gathers (lo/hi src ranges) ----
    t1_kernel<<<dim3(GBLK, 2), 256, 0, stream>>>(rx, lx, emb, W1, disR, disL, hs1R, hs1L);
    ga_kernel<<<2 * GHALF, 256, 0, stream>>>(metaR, metaL, slabR, slabL,
                                             hs1R, hs1L, partR, partL);
    g1b_kernel<<<2 * GHALF, 256, 0, stream>>>(metaR, metaL, slabR, slabL,
                                              hs1R, hs1L, disR, disL, b1, W2,
                                              partR, partL, hs2R, hs2L);
    ga_kernel<<<2 * GHALF, 256, 0, stream>>>(metaR, metaL, slabR, slabL,
                                             hs2R, hs2L, partR, partL);
    g2b_kernel<<<2 * GHALF, 256, 0, stream>>>(metaR, metaL, slabR, slabL,
                                              hs2R, hs2L, disR, disL, b2, rb, lb,
                                              partR, partL, sums0, sums1, cnt0, cnt1);
    final_kernel<<<(N_GRAPHS + 255) / 256, 256, 0, stream>>>(
        sums0, cnt0, sums1, cnt1, fcW, fcb, out);
}